// Round 1
// baseline (818.154 us; speedup 1.0000x reference)
//
#include <hip/hip_runtime.h>
#include <hip/hip_bf16.h>
#include <stdint.h>

#define B_   64
#define T_   512
#define NIN_ 256
#define N_   512

typedef _Float16 half2_t __attribute__((ext_vector_type(2)));

#if defined(__has_builtin)
#if __has_builtin(__builtin_amdgcn_fdot2)
#define HAVE_FDOT2 1
#endif
#endif

__device__ __forceinline__ float dot2acc(unsigned int a, unsigned int b, float c) {
#ifdef HAVE_FDOT2
  return __builtin_amdgcn_fdot2(__builtin_bit_cast(half2_t, a),
                                __builtin_bit_cast(half2_t, b), c, false);
#else
  half2_t ha = __builtin_bit_cast(half2_t, a), hb = __builtin_bit_cast(half2_t, b);
  c += (float)ha[0] * (float)hb[0];
  c += (float)ha[1] * (float)hb[1];
  return c;
#endif
}

__device__ __forceinline__ float fast_tanh(float x) {
  // tanh(x) = 1 - 2/(exp(2x)+1); saturates correctly for |x| large.
  float e = __expf(2.0f * x);
  return 1.0f - 2.0f / (e + 1.0f);
}

// ---------------- Phase 1: xp[b,t,n] = sum_c x[b,t,c] * Wih[n,c] -> out ----
// M = B*T = 32768 rows, N = 512, K = 256. 128x128 tile, 8x8 micro, BK=32.
__global__ __launch_bounds__(256) void xproj(const float* __restrict__ x,
                                             const float* __restrict__ Wih,
                                             float* __restrict__ out) {
  const int tid = threadIdx.x;
  const int bm = blockIdx.x;   // 0..255  (M/128)
  const int bn = blockIdx.y;   // 0..3    (N/128)
  const int tm = tid & 15;
  const int tn = tid >> 4;
  const int m0 = bm << 7;
  const int n0 = bn << 7;

  __shared__ float xt[32][132];   // k-major, pad 132 for bank spread
  __shared__ float wt[32][132];

  float acc[8][8];
#pragma unroll
  for (int i = 0; i < 8; ++i) {
#pragma unroll
    for (int j = 0; j < 8; ++j) acc[i][j] = 0.f;
  }

  for (int ko = 0; ko < NIN_; ko += 32) {
#pragma unroll
    for (int it = 0; it < 4; ++it) {
      const int fidx = it * 256 + tid;       // 1024 float4s = 128 rows x 32 k
      const int mm = fidx >> 3;              // 0..127
      const int k4 = (fidx & 7) << 2;        // 0,4,...,28
      const float4 vx = *(const float4*)(x + (size_t)(m0 + mm) * NIN_ + ko + k4);
      xt[k4 + 0][mm] = vx.x; xt[k4 + 1][mm] = vx.y;
      xt[k4 + 2][mm] = vx.z; xt[k4 + 3][mm] = vx.w;
      const float4 vw = *(const float4*)(Wih + (size_t)(n0 + mm) * NIN_ + ko + k4);
      wt[k4 + 0][mm] = vw.x; wt[k4 + 1][mm] = vw.y;
      wt[k4 + 2][mm] = vw.z; wt[k4 + 3][mm] = vw.w;
    }
    __syncthreads();
#pragma unroll 4
    for (int kk = 0; kk < 32; ++kk) {
      float a[8], b[8];
      *(float4*)&a[0] = *(const float4*)&xt[kk][8 * tm];
      *(float4*)&a[4] = *(const float4*)&xt[kk][8 * tm + 4];
      *(float4*)&b[0] = *(const float4*)&wt[kk][8 * tn];
      *(float4*)&b[4] = *(const float4*)&wt[kk][8 * tn + 4];
#pragma unroll
      for (int i = 0; i < 8; ++i) {
#pragma unroll
        for (int j = 0; j < 8; ++j) acc[i][j] = fmaf(a[i], b[j], acc[i][j]);
      }
    }
    __syncthreads();
  }

#pragma unroll
  for (int i = 0; i < 8; ++i) {
    float4 v0 = make_float4(acc[i][0], acc[i][1], acc[i][2], acc[i][3]);
    float4 v1 = make_float4(acc[i][4], acc[i][5], acc[i][6], acc[i][7]);
    float* p = out + (size_t)(m0 + 8 * tm + i) * N_ + n0 + 8 * tn;
    *(float4*)p = v0;
    *((float4*)p + 1) = v1;
  }
}

// ---------------- Phase 2: recurrent scan ---------------------------------
// 256 blocks x 512 threads. block = m*64 + b: batch b, neuron slice m (128 n).
// W_hh slice lives packed-f16 in VGPRs (64 regs/lane). tanh(h) exchanged
// between the 4 peer wgs of a batch as (tag<<32 | f16x2) relaxed agent atomics.
__global__ __launch_bounds__(512, 1) void rnn_scan(const float* __restrict__ Whh,
                                                   float* __restrict__ out,
                                                   unsigned long long* __restrict__ ex) {
  const int blk = blockIdx.x;
  const int m = blk >> 6;        // slice 0..3
  const int b = blk & 63;        // batch
  const int tid = threadIdx.x;
  const int wv = tid >> 6;       // wave 0..7
  const int lane = tid & 63;
  const int g = wv >> 2;         // 0..1  (64-neuron group)
  const int q = wv & 3;          // 0..3  (k quarter)
  const int nloc = g * 64 + lane;        // 0..127
  const int ng = m * 128 + nloc;         // global neuron

  // Load W_hh[ng][q*128 .. q*128+127] as 64 packed f16 pairs (once).
  unsigned int w[64];
  {
    const float* wr = Whh + (size_t)ng * N_ + q * 128;
#pragma unroll
    for (int j = 0; j < 64; ++j) {
      half2_t h;
      h[0] = (_Float16)wr[2 * j];
      h[1] = (_Float16)wr[2 * j + 1];
      w[j] = __builtin_bit_cast(unsigned int, h);
    }
  }

  __shared__ uint4 thp4[64];     // 256 f16-pairs = tanh(h_{t-1})[0..511]
  __shared__ float red[8][64];   // per-wave partial sums
  __shared__ float thf[128];     // tanh of this slice's new h

  float* outb = out + (size_t)b * T_ * N_;
  unsigned long long* exb = ex + (size_t)b * 2 * 256;

  for (int t = 1; t < T_; ++t) {
    // prefetch my xp (phase-1 data in my own slice; only I overwrite it later)
    float xp = 0.f;
    if (tid < 128) xp = outb[(size_t)t * N_ + m * 128 + tid];

    if (t == 1) {
      // h_0 stored at out[b][0][:] by phase 1 (kernel-boundary visibility)
      if (tid < 256) {
        float2 h0 = *(const float2*)(outb + 2 * tid);
        half2_t hp;
        hp[0] = (_Float16)fast_tanh(h0.x);
        hp[1] = (_Float16)fast_tanh(h0.y);
        ((unsigned int*)thp4)[tid] = __builtin_bit_cast(unsigned int, hp);
      }
    } else {
      // poll the 192 remote pairs (own 64 already written last iteration)
      if (tid < 192) {
        const int pr = tid + (tid >= m * 64 ? 64 : 0);
        const int slot = (t - 1) & 1;
        unsigned long long v;
        for (;;) {
          v = __hip_atomic_load(&exb[slot * 256 + pr], __ATOMIC_RELAXED,
                                __HIP_MEMORY_SCOPE_AGENT);
          if ((unsigned int)(v >> 32) == (unsigned int)(t - 1)) break;
          __builtin_amdgcn_s_sleep(1);
        }
        ((unsigned int*)thp4)[pr] = (unsigned int)v;
      }
    }
    __syncthreads();   // A: thp4 complete

    // y_partial[ng] over k in [q*128, q*128+128)
    float acc = 0.f;
    const uint4* tq = &thp4[q * 16];
#pragma unroll
    for (int j4 = 0; j4 < 16; ++j4) {
      uint4 tv = tq[j4];
      acc = dot2acc(w[4 * j4 + 0], tv.x, acc);
      acc = dot2acc(w[4 * j4 + 1], tv.y, acc);
      acc = dot2acc(w[4 * j4 + 2], tv.z, acc);
      acc = dot2acc(w[4 * j4 + 3], tv.w, acc);
    }
    red[wv][lane] = acc;
    __syncthreads();   // B: partials ready

    if (tid < 128) {
      const int gg = tid >> 6, ll = tid & 63;
      float y = red[gg * 4 + 0][ll] + red[gg * 4 + 1][ll] +
                red[gg * 4 + 2][ll] + red[gg * 4 + 3][ll] + xp;
      outb[(size_t)t * N_ + m * 128 + tid] = y;   // final output (plain store)
      thf[tid] = fast_tanh(y);
    }
    __syncthreads();   // C: thf ready

    if (tid < 64) {
      half2_t hp;
      hp[0] = (_Float16)thf[2 * tid];
      hp[1] = (_Float16)thf[2 * tid + 1];
      const unsigned int pk = __builtin_bit_cast(unsigned int, hp);
      ((unsigned int*)thp4)[m * 64 + tid] = pk;   // my slice for next iter
      const int slot = t & 1;
      __hip_atomic_store(&exb[slot * 256 + m * 64 + tid],
                         ((unsigned long long)(unsigned int)t << 32) | pk,
                         __ATOMIC_RELAXED, __HIP_MEMORY_SCOPE_AGENT);
    }
    // next iteration's barrier A separates these writes from compute reads
  }
}

extern "C" void kernel_launch(void* const* d_in, const int* in_sizes, int n_in,
                              void* d_out, int out_size, void* d_ws, size_t ws_size,
                              hipStream_t stream) {
  const float* x   = (const float*)d_in[0];
  const float* Wih = (const float*)d_in[1];
  const float* Whh = (const float*)d_in[2];
  float* out = (float*)d_out;
  unsigned long long* ex = (unsigned long long*)d_ws;

  // exchange buffer: 64 batches x 2 slots x 256 pairs x 8B = 256 KiB
  hipMemsetAsync(d_ws, 0, (size_t)B_ * 2 * 256 * 8, stream);

  dim3 g1(256, 4);
  xproj<<<g1, 256, 0, stream>>>(x, Wih, out);
  rnn_scan<<<256, 512, 0, stream>>>(Whh, out, ex);
}